// Round 3
// baseline (45.909 us; speedup 1.0000x reference)
//
#include <hip/hip_runtime.h>

typedef float v2f __attribute__((ext_vector_type(2)));
typedef float v4f __attribute__((ext_vector_type(4)));

#define NPTS   4096
#define CHUNK  256                 // points staged per block
#define G4     (CHUNK / 4)         // 64 groups of 4 points
#define QPT    16                  // queries per thread
#define TPB    128
#define QPB    (TPB * QPT)         // 2048 queries per block
#define NCHUNK (NPTS / CHUNK)      // 16
#define NZ     16                  // B * 2 passes

__device__ __forceinline__ v2f pk_fma(v2f a, v2f b, v2f c) {
    v2f d;
    asm("v_pk_fma_f32 %0, %1, %2, %3" : "=v"(d) : "v"(a), "v"(b), "v"(c));
    return d;
}
__device__ __forceinline__ float min3f(float a, float b, float c) {
    float d;
    asm("v_min3_f32 %0, %1, %2, %3" : "=v"(d) : "v"(a), "v"(b), "v"(c));
    return d;
}

// One dispatch covers BOTH chamfer directions (blockIdx.z = b*2 + pass).
// Each block: stage CHUNK points (SoA 4-point groups, w = |p|^2 folded in),
// each thread computes min over the chunk for QPT queries, writes partial min.
__global__ __launch_bounds__(TPB, 2) void min_kernel(const float* __restrict__ preds,
                                                     const float* __restrict__ gts,
                                                     float* __restrict__ partial) {
    const int z    = blockIdx.z;          // b*2 + pass
    const int b    = z >> 1;
    const int pass = z & 1;
    const float* pts = pass ? preds : gts;   // pass0: min over gts (per pred)
    const float* qrs = pass ? gts   : preds; // pass1: min over preds (per gt)

    const int chunk = blockIdx.y;
    const int i0    = chunk * CHUNK;
    const int tid   = threadIdx.x;

    __shared__ v4f SX[G4], SY[G4], SZ[G4], SW[G4];

    // ---- stage CHUNK points, transposed to 4-point SoA groups ----
    {
        const float* pb = pts + ((size_t)b * NPTS + i0) * 3;
        for (int idx = tid; idx < CHUNK; idx += TPB) {
            float x  = pb[idx * 3 + 0];
            float y  = pb[idx * 3 + 1];
            float zz = pb[idx * 3 + 2];
            float w  = fmaf(x, x, fmaf(y, y, zz * zz));
            ((float*)SX)[idx] = x;
            ((float*)SY)[idx] = y;
            ((float*)SZ)[idx] = zz;
            ((float*)SW)[idx] = w;
        }
    }

    // ---- load QPT queries, precompute -2q broadcast pairs ----
    const float* qb    = qrs + (size_t)b * NPTS * 3;
    const int    jbase = blockIdx.x * QPB + tid;
    v2f   AX[QPT], AY[QPT], AZ[QPT];
    float R[QPT], acc[QPT];
#pragma unroll
    for (int q = 0; q < QPT; ++q) {
        int   j  = jbase + q * TPB;
        float qx = qb[j * 3 + 0];
        float qy = qb[j * 3 + 1];
        float qz = qb[j * 3 + 2];
        R[q]   = fmaf(qx, qx, fmaf(qy, qy, qz * qz));
        float ax = -2.0f * qx, ay = -2.0f * qy, az = -2.0f * qz;
        AX[q] = (v2f){ax, ax};
        AY[q] = (v2f){ay, ay};
        AZ[q] = (v2f){az, az};
        acc[q] = 3.4e38f;
    }
    __syncthreads();

    // ---- main loop: 4 points x QPT queries per group ----
#pragma unroll 2
    for (int g = 0; g < G4; ++g) {
        v4f X = SX[g], Y = SY[g], Z = SZ[g], W = SW[g];
        v2f xlo = X.lo, xhi = X.hi;
        v2f ylo = Y.lo, yhi = Y.hi;
        v2f zlo = Z.lo, zhi = Z.hi;
        v2f wlo = W.lo, whi = W.hi;
#pragma unroll
        for (int q = 0; q < QPT; ++q) {
            v2f t0 = pk_fma(xlo, AX[q], pk_fma(ylo, AY[q], pk_fma(zlo, AZ[q], wlo)));
            v2f t1 = pk_fma(xhi, AX[q], pk_fma(yhi, AY[q], pk_fma(zhi, AZ[q], whi)));
            acc[q] = min3f(t0.x, t0.y, min3f(t1.x, t1.y, acc[q]));
        }
    }

    // ---- write partial mins (one slot per (z, chunk, query): no atomics) ----
    float* dst = partial + ((size_t)z * NCHUNK + chunk) * NPTS;
#pragma unroll
    for (int q = 0; q < QPT; ++q) {
        dst[jbase + q * TPB] = R[q] + acc[q];
    }
}

// min over the NCHUNK partials per query, huber, block-sum.
__global__ __launch_bounds__(256) void huber_kernel(const float* __restrict__ partial,
                                                    const float* __restrict__ cp,
                                                    float* __restrict__ bp) {
    const int s = blockIdx.x * 256 + threadIdx.x;   // [0, NZ*NPTS)
    const int z = s >> 12, j = s & (NPTS - 1);
    const float* p = partial + (size_t)z * NCHUNK * NPTS + j;
    float m = 3.4e38f;
#pragma unroll
    for (int c = 0; c < NCHUNK; ++c) m = fminf(m, p[(size_t)c * NPTS]);
    const float cc = cp[0];
    float h = (m < cc) ? (0.5f * m * m) : fmaf(cc, m, -0.5f * cc * cc);
    for (int off = 32; off > 0; off >>= 1) h += __shfl_down(h, off, 64);
    __shared__ float ls[4];
    if ((threadIdx.x & 63) == 0) ls[threadIdx.x >> 6] = h;
    __syncthreads();
    if (threadIdx.x == 0) bp[blockIdx.x] = ls[0] + ls[1] + ls[2] + ls[3];
}

__global__ __launch_bounds__(256) void final_kernel(const float* __restrict__ bp,
                                                    float* __restrict__ out) {
    float a = bp[threadIdx.x];   // exactly 256 block partials
    for (int off = 32; off > 0; off >>= 1) a += __shfl_down(a, off, 64);
    __shared__ float ls[4];
    if ((threadIdx.x & 63) == 0) ls[threadIdx.x >> 6] = a;
    __syncthreads();
    if (threadIdx.x == 0) out[0] = ls[0] + ls[1] + ls[2] + ls[3];
}

extern "C" void kernel_launch(void* const* d_in, const int* in_sizes, int n_in,
                              void* d_out, int out_size, void* d_ws, size_t ws_size,
                              hipStream_t stream) {
    const float* preds = (const float*)d_in[0];  // [8, 4096, 3]
    const float* gts   = (const float*)d_in[1];  // [8, 4096, 3]
    const float* cp    = (const float*)d_in[2];  // [1]
    float* out = (float*)d_out;

    float* partial = (float*)d_ws;                            // [NZ][NCHUNK][NPTS] = 4 MB
    float* bp      = partial + (size_t)NZ * NCHUNK * NPTS;    // [256]

    dim3 gm(NPTS / QPB, NCHUNK, NZ);   // (2, 16, 16) = 512 blocks
    min_kernel<<<gm, TPB, 0, stream>>>(preds, gts, partial);

    huber_kernel<<<(NZ * NPTS) / 256, 256, 0, stream>>>(partial, cp, bp);
    final_kernel<<<1, 256, 0, stream>>>(bp, out);
}

// Round 7
// 42.065 us; speedup vs baseline: 1.0914x; 1.0914x over previous
//
#include <hip/hip_runtime.h>

typedef float v2f  __attribute__((ext_vector_type(2)));
typedef float v4f  __attribute__((ext_vector_type(4)));

#define NPTS   4096
#define NB     8
#define NZ     16                  // B * 2 passes
#define QPT    8                   // queries per thread
#define TPB    256
#define QPB    (TPB * QPT)         // 2048
#define XB     (NPTS / QPB)        // 2
#define RANGE  128                 // points per block
#define NGRP   (RANGE / 4)         // 32 groups of 4 points per block
#define NRANGE (NPTS / RANGE)      // 32

// ---- order-preserving float <-> uint encoding (for atomicMin on floats) ----
__device__ __forceinline__ unsigned enc_f(float f) {
    unsigned u = __float_as_uint(f);
    return (u & 0x80000000u) ? ~u : (u | 0x80000000u);
}
__device__ __forceinline__ float dec_f(unsigned e) {
    unsigned u = (e & 0x80000000u) ? (e ^ 0x80000000u) : ~e;
    return __uint_as_float(u);
}

// VOP3P pk_fma: all three sources must be 64-bit VGPR pairs
__device__ __forceinline__ v2f pk_fma(v2f a, v2f b, v2f c) {
    v2f d;
    asm("v_pk_fma_f32 %0, %1, %2, %3" : "=v"(d) : "v"(a), "v"(b), "v"(c));
    return d;
}
__device__ __forceinline__ float min3f(float a, float b, float c) {
    float d;
    asm("v_min3_f32 %0, %1, %2, %3" : "=v"(d) : "v"(a), "v"(b), "v"(c));
    return d;
}

// Transpose both point sets into 64B SoA groups {x0..3,y0..3,z0..3,w0..3}
// (w = |p|^2), and init the encoded-min array. 65536 threads exactly.
__global__ __launch_bounds__(256) void prep_kernel(const float* __restrict__ preds,
                                                   const float* __restrict__ gts,
                                                   float* __restrict__ ptsT,
                                                   unsigned* __restrict__ mins) {
    const int t = blockIdx.x * 256 + threadIdx.x;
    mins[t] = 0xFFFFFFFFu;   // +inf encoded; mins has NZ*NPTS = 65536 entries
    if (t < 2 * NB * (NPTS / 4)) {          // 16384 groups
        const int arr = t >> 13;            // 0: gts (pass0 points), 1: preds
        const float* src = (arr ? preds : gts) + (size_t)(t & 8191) * 12;
        v4f f0 = *(const v4f*)(src + 0);
        v4f f1 = *(const v4f*)(src + 4);
        v4f f2 = *(const v4f*)(src + 8);
        float x0=f0.x, y0=f0.y, z0=f0.z, x1=f0.w;
        float y1=f1.x, z1=f1.y, x2=f1.z, y2=f1.w;
        float z2=f2.x, x3=f2.y, y3=f2.z, z3=f2.w;
        v4f X = {x0, x1, x2, x3};
        v4f Y = {y0, y1, y2, y3};
        v4f Z = {z0, z1, z2, z3};
        v4f W = {fmaf(x0,x0,fmaf(y0,y0,z0*z0)), fmaf(x1,x1,fmaf(y1,y1,z1*z1)),
                 fmaf(x2,x2,fmaf(y2,y2,z2*z2)), fmaf(x3,x3,fmaf(y3,y3,z3*z3))};
        v4f* dst = (v4f*)(ptsT + (size_t)t * 16);
        dst[0] = X; dst[1] = Y; dst[2] = Z; dst[3] = W;
    }
}

// blockIdx: x = query slice (2), y = point range (32), z = b*2 + pass (16).
// Point groups are read at wave-uniform addresses from the L2-resident ptsT
// (compiler picks s_load or uniform global_load and inserts correct waits).
// Queries live in VGPRs. Partial mins combined via encoded atomicMin.
__global__ __launch_bounds__(TPB, 2) void min_kernel(const float* __restrict__ preds,
                                                     const float* __restrict__ gts,
                                                     const float* __restrict__ ptsT,
                                                     unsigned* __restrict__ mins) {
    const int z    = blockIdx.z;
    const int b    = z >> 1;
    const int pass = z & 1;
    const int tid  = threadIdx.x;

    // pass0: points=gts(arr0), queries=preds ; pass1: points=preds(arr1), queries=gts
    const v4f* gp = (const v4f*)ptsT
                  + ((size_t)(pass * NB + b) * (NPTS / 4) + blockIdx.y * NGRP) * 4;
    const float* qb = (pass ? gts : preds) + (size_t)b * NPTS * 3;

    // ---- per-thread queries (duplicated pairs for VOP3P) ----
    const int jbase = blockIdx.x * QPB + tid;
    v2f   AX[QPT], AY[QPT], AZ[QPT];
    float R[QPT], acc[QPT];
#pragma unroll
    for (int q = 0; q < QPT; ++q) {
        int   j  = jbase + q * TPB;
        float qx = qb[j * 3 + 0];
        float qy = qb[j * 3 + 1];
        float qz = qb[j * 3 + 2];
        R[q]  = fmaf(qx, qx, fmaf(qy, qy, qz * qz));
        float ax = -2.0f * qx, ay = -2.0f * qy, az = -2.0f * qz;
        AX[q] = (v2f){ax, ax};
        AY[q] = (v2f){ay, ay};
        AZ[q] = (v2f){az, az};
        acc[q] = 3.4e38f;
    }

    // ---- stream NGRP point groups (wave-uniform loads, unroll-4 prefetch) ----
#pragma unroll 4
    for (int g = 0; g < NGRP; ++g) {
        v4f X = gp[g * 4 + 0];
        v4f Y = gp[g * 4 + 1];
        v4f Z = gp[g * 4 + 2];
        v4f W = gp[g * 4 + 3];
        v2f Xlo = X.lo, Xhi = X.hi;
        v2f Ylo = Y.lo, Yhi = Y.hi;
        v2f Zlo = Z.lo, Zhi = Z.hi;
        v2f Wlo = W.lo, Whi = W.hi;
#pragma unroll
        for (int q = 0; q < QPT; ++q) {
            v2f t0 = pk_fma(Xlo, AX[q], pk_fma(Ylo, AY[q], pk_fma(Zlo, AZ[q], Wlo)));
            v2f t1 = pk_fma(Xhi, AX[q], pk_fma(Yhi, AY[q], pk_fma(Zhi, AZ[q], Whi)));
            acc[q] = min3f(t0.x, t0.y, min3f(t1.x, t1.y, acc[q]));
        }
    }

    // ---- combine across point-ranges ----
    unsigned* mz = mins + (size_t)z * NPTS;
#pragma unroll
    for (int q = 0; q < QPT; ++q) {
        atomicMin(&mz[jbase + q * TPB], enc_f(R[q] + acc[q]));
    }
}

// Single block: decode mins, huber, deterministic tree-sum -> out[0].
__global__ __launch_bounds__(1024) void huberfinal_kernel(const unsigned* __restrict__ mins,
                                                          const float* __restrict__ cp,
                                                          float* __restrict__ out) {
    const float c = cp[0];
    float acc = 0.0f;
#pragma unroll 4
    for (int i = threadIdx.x; i < NZ * NPTS; i += 1024) {
        float x = dec_f(mins[i]);
        acc += (x < c) ? (0.5f * x * x) : fmaf(c, x, -0.5f * c * c);
    }
    for (int off = 32; off > 0; off >>= 1) acc += __shfl_down(acc, off, 64);
    __shared__ float ls[16];
    if ((threadIdx.x & 63) == 0) ls[threadIdx.x >> 6] = acc;
    __syncthreads();
    if (threadIdx.x == 0) {
        float s = 0.0f;
#pragma unroll
        for (int w = 0; w < 16; ++w) s += ls[w];
        out[0] = s;
    }
}

extern "C" void kernel_launch(void* const* d_in, const int* in_sizes, int n_in,
                              void* d_out, int out_size, void* d_ws, size_t ws_size,
                              hipStream_t stream) {
    const float* preds = (const float*)d_in[0];  // [8, 4096, 3]
    const float* gts   = (const float*)d_in[1];  // [8, 4096, 3]
    const float* cp    = (const float*)d_in[2];  // [1]
    float* out = (float*)d_out;

    float*    ptsT = (float*)d_ws;                         // 2*8*1024*16 floats = 1 MB
    unsigned* mins = (unsigned*)(ptsT + (size_t)2 * NB * (NPTS / 4) * 16);  // 256 KB

    prep_kernel<<<(NZ * NPTS) / 256, 256, 0, stream>>>(preds, gts, ptsT, mins);

    dim3 gm(XB, NRANGE, NZ);   // (2, 32, 16) = 1024 blocks
    min_kernel<<<gm, TPB, 0, stream>>>(preds, gts, ptsT, mins);

    huberfinal_kernel<<<1, 1024, 0, stream>>>(mins, cp, out);
}

// Round 8
// 39.855 us; speedup vs baseline: 1.1519x; 1.0555x over previous
//
#include <hip/hip_runtime.h>

typedef float v2f  __attribute__((ext_vector_type(2)));
typedef float v4f  __attribute__((ext_vector_type(4)));

#define NPTS   4096
#define NB     8
#define NZ     16                  // B * 2 passes
#define QPT    8                   // queries per thread
#define TPB    256
#define QPB    (TPB * QPT)         // 2048
#define XB     (NPTS / QPB)        // 2
#define CHUNK  128                 // points staged per block
#define NGRP   (CHUNK / 4)         // 32 groups of 4 points
#define NCHUNK (NPTS / CHUNK)      // 32

// ---- order-preserving float <-> uint encoding (for atomicMin on floats) ----
__device__ __forceinline__ unsigned enc_f(float f) {
    unsigned u = __float_as_uint(f);
    return (u & 0x80000000u) ? ~u : (u | 0x80000000u);
}
__device__ __forceinline__ float dec_f(unsigned e) {
    unsigned u = (e & 0x80000000u) ? (e ^ 0x80000000u) : ~e;
    return __uint_as_float(u);
}

// VOP3P: all pair sources must be 64-bit VGPR pairs (no scalar/SGPR src)
__device__ __forceinline__ v2f pk_fma(v2f a, v2f b, v2f c) {
    v2f d;
    asm("v_pk_fma_f32 %0, %1, %2, %3" : "=v"(d) : "v"(a), "v"(b), "v"(c));
    return d;
}
__device__ __forceinline__ v2f pk_mul(v2f a, v2f b) {
    v2f d;
    asm("v_pk_mul_f32 %0, %1, %2" : "=v"(d) : "v"(a), "v"(b));
    return d;
}
__device__ __forceinline__ float min3f(float a, float b, float c) {
    float d;
    asm("v_min3_f32 %0, %1, %2, %3" : "=v"(d) : "v"(a), "v"(b), "v"(c));
    return d;
}

// blockIdx: x = query slice (2), y = point chunk (32), z = b*2 + pass (16).
// Stage CHUNK points into LDS as 4-point SoA groups (X,Y,Z only; |p|^2 is
// recomputed per group, amortized over QPT queries). Each thread computes the
// chunk-min for QPT queries; chunks combine via encoded atomicMin.
__global__ __launch_bounds__(TPB, 2) void min_kernel(const float* __restrict__ preds,
                                                     const float* __restrict__ gts,
                                                     unsigned* __restrict__ mins) {
    const int z    = blockIdx.z;
    const int b    = z >> 1;
    const int pass = z & 1;
    const int tid  = threadIdx.x;

    const float* pts = pass ? preds : gts;   // pass0: min over gts (per pred)
    const float* qrs = pass ? gts   : preds; // pass1: min over preds (per gt)

    __shared__ v4f SX[NGRP], SY[NGRP], SZ[NGRP];

    // ---- stage CHUNK points, transposed to 4-point SoA groups ----
    {
        const float* pb = pts + ((size_t)b * NPTS + blockIdx.y * CHUNK) * 3;
        if (tid < CHUNK) {
            ((float*)SX)[tid] = pb[tid * 3 + 0];
            ((float*)SY)[tid] = pb[tid * 3 + 1];
            ((float*)SZ)[tid] = pb[tid * 3 + 2];
        }
    }

    // ---- per-thread queries (duplicated pairs for VOP3P) ----
    const float* qb    = qrs + (size_t)b * NPTS * 3;
    const int    jbase = blockIdx.x * QPB + tid;
    v2f   AX[QPT], AY[QPT], AZ[QPT];
    float R[QPT], acc[QPT];
#pragma unroll
    for (int q = 0; q < QPT; ++q) {
        int   j  = jbase + q * TPB;
        float qx = qb[j * 3 + 0];
        float qy = qb[j * 3 + 1];
        float qz = qb[j * 3 + 2];
        R[q]  = fmaf(qx, qx, fmaf(qy, qy, qz * qz));
        float ax = -2.0f * qx, ay = -2.0f * qy, az = -2.0f * qz;
        AX[q] = (v2f){ax, ax};
        AY[q] = (v2f){ay, ay};
        AZ[q] = (v2f){az, az};
        acc[q] = 3.4e38f;
    }
    __syncthreads();

    // ---- main loop: 4 points x QPT queries per group (broadcast LDS reads) ----
#pragma unroll 2
    for (int g = 0; g < NGRP; ++g) {
        v4f X = SX[g], Y = SY[g], Z = SZ[g];
        v2f Xlo = X.lo, Xhi = X.hi;
        v2f Ylo = Y.lo, Yhi = Y.hi;
        v2f Zlo = Z.lo, Zhi = Z.hi;
        // |p|^2 recomputed (3 packed ops amortized over QPT queries)
        v2f Wlo = pk_fma(Xlo, Xlo, pk_fma(Ylo, Ylo, pk_mul(Zlo, Zlo)));
        v2f Whi = pk_fma(Xhi, Xhi, pk_fma(Yhi, Yhi, pk_mul(Zhi, Zhi)));
#pragma unroll
        for (int q = 0; q < QPT; ++q) {
            v2f t0 = pk_fma(Xlo, AX[q], pk_fma(Ylo, AY[q], pk_fma(Zlo, AZ[q], Wlo)));
            v2f t1 = pk_fma(Xhi, AX[q], pk_fma(Yhi, AY[q], pk_fma(Zhi, AZ[q], Whi)));
            acc[q] = min3f(t0.x, t0.y, min3f(t1.x, t1.y, acc[q]));
        }
    }

    // ---- combine across chunks ----
    unsigned* mz = mins + (size_t)z * NPTS;
#pragma unroll
    for (int q = 0; q < QPT; ++q) {
        atomicMin(&mz[jbase + q * TPB], enc_f(R[q] + acc[q]));
    }
}

// Single block: decode mins, huber, deterministic tree-sum -> out[0].
__global__ __launch_bounds__(1024) void huberfinal_kernel(const unsigned* __restrict__ mins,
                                                          const float* __restrict__ cp,
                                                          float* __restrict__ out) {
    const float c = cp[0];
    float acc = 0.0f;
#pragma unroll 4
    for (int i = threadIdx.x; i < NZ * NPTS; i += 1024) {
        float x = dec_f(mins[i]);
        acc += (x < c) ? (0.5f * x * x) : fmaf(c, x, -0.5f * c * c);
    }
    for (int off = 32; off > 0; off >>= 1) acc += __shfl_down(acc, off, 64);
    __shared__ float ls[16];
    if ((threadIdx.x & 63) == 0) ls[threadIdx.x >> 6] = acc;
    __syncthreads();
    if (threadIdx.x == 0) {
        float s = 0.0f;
#pragma unroll
        for (int w = 0; w < 16; ++w) s += ls[w];
        out[0] = s;
    }
}

extern "C" void kernel_launch(void* const* d_in, const int* in_sizes, int n_in,
                              void* d_out, int out_size, void* d_ws, size_t ws_size,
                              hipStream_t stream) {
    const float* preds = (const float*)d_in[0];  // [8, 4096, 3]
    const float* gts   = (const float*)d_in[1];  // [8, 4096, 3]
    const float* cp    = (const float*)d_in[2];  // [1]
    float* out = (float*)d_out;

    unsigned* mins = (unsigned*)d_ws;            // [NZ][NPTS] encoded floats, 256 KB

    // 0xFF bytes == 0xFFFFFFFFu == encoded +inf
    hipMemsetAsync(mins, 0xFF, (size_t)NZ * NPTS * sizeof(unsigned), stream);

    dim3 gm(XB, NCHUNK, NZ);   // (2, 32, 16) = 1024 blocks
    min_kernel<<<gm, TPB, 0, stream>>>(preds, gts, mins);

    huberfinal_kernel<<<1, 1024, 0, stream>>>(mins, cp, out);
}

// Round 9
// 33.398 us; speedup vs baseline: 1.3746x; 1.1933x over previous
//
#include <hip/hip_runtime.h>

typedef float v2f  __attribute__((ext_vector_type(2)));
typedef float v4f  __attribute__((ext_vector_type(4)));

#define NPTS   4096
#define NZ     16                  // B * 2 passes
#define QPT    8                   // queries per thread
#define TPB    256
#define QPB    (TPB * QPT)         // 2048
#define XB     (NPTS / QPB)        // 2
#define CHUNK  128                 // points staged per block
#define NGRP   (CHUNK / 4)         // 32 groups of 4 points
#define NCHUNK (NPTS / CHUNK)      // 32

// VOP3P: all pair sources must be 64-bit VGPR pairs (no scalar/SGPR src)
__device__ __forceinline__ v2f pk_fma(v2f a, v2f b, v2f c) {
    v2f d;
    asm("v_pk_fma_f32 %0, %1, %2, %3" : "=v"(d) : "v"(a), "v"(b), "v"(c));
    return d;
}
__device__ __forceinline__ v2f pk_mul(v2f a, v2f b) {
    v2f d;
    asm("v_pk_mul_f32 %0, %1, %2" : "=v"(d) : "v"(a), "v"(b));
    return d;
}
__device__ __forceinline__ float min3f(float a, float b, float c) {
    float d;
    asm("v_min3_f32 %0, %1, %2, %3" : "=v"(d) : "v"(a), "v"(b), "v"(c));
    return d;
}

// blockIdx: x = query slice (2), y = point chunk (32), z = b*2 + pass (16).
// Stage CHUNK points into LDS as 4-point SoA groups (X,Y,Z; |p|^2 recomputed
// per group, amortized over QPT queries). Each thread computes the chunk-min
// for QPT queries and stores to a unique partial slot (no atomics).
__global__ __launch_bounds__(TPB, 4) void min_kernel(const float* __restrict__ preds,
                                                     const float* __restrict__ gts,
                                                     float* __restrict__ partial) {
    const int z    = blockIdx.z;
    const int b    = z >> 1;
    const int pass = z & 1;
    const int tid  = threadIdx.x;

    const float* pts = pass ? preds : gts;   // pass0: min over gts (per pred)
    const float* qrs = pass ? gts   : preds; // pass1: min over preds (per gt)

    __shared__ v4f SX[NGRP], SY[NGRP], SZ[NGRP];

    // ---- stage CHUNK points, transposed to 4-point SoA groups ----
    {
        const float* pb = pts + ((size_t)b * NPTS + blockIdx.y * CHUNK) * 3;
        if (tid < CHUNK) {
            ((float*)SX)[tid] = pb[tid * 3 + 0];
            ((float*)SY)[tid] = pb[tid * 3 + 1];
            ((float*)SZ)[tid] = pb[tid * 3 + 2];
        }
    }

    // ---- per-thread queries (duplicated pairs for VOP3P) ----
    const float* qb    = qrs + (size_t)b * NPTS * 3;
    const int    jbase = blockIdx.x * QPB + tid;
    v2f   AX[QPT], AY[QPT], AZ[QPT];
    float R[QPT], acc[QPT];
#pragma unroll
    for (int q = 0; q < QPT; ++q) {
        int   j  = jbase + q * TPB;
        float qx = qb[j * 3 + 0];
        float qy = qb[j * 3 + 1];
        float qz = qb[j * 3 + 2];
        R[q]  = fmaf(qx, qx, fmaf(qy, qy, qz * qz));
        float ax = -2.0f * qx, ay = -2.0f * qy, az = -2.0f * qz;
        AX[q] = (v2f){ax, ax};
        AY[q] = (v2f){ay, ay};
        AZ[q] = (v2f){az, az};
        acc[q] = 3.4e38f;
    }
    __syncthreads();

    // ---- main loop: 4 points x QPT queries per group (broadcast LDS reads) ----
#pragma unroll 2
    for (int g = 0; g < NGRP; ++g) {
        v4f X = SX[g], Y = SY[g], Z = SZ[g];
        v2f Xlo = X.lo, Xhi = X.hi;
        v2f Ylo = Y.lo, Yhi = Y.hi;
        v2f Zlo = Z.lo, Zhi = Z.hi;
        // |p|^2 recomputed (6 packed ops amortized over QPT queries)
        v2f Wlo = pk_fma(Xlo, Xlo, pk_fma(Ylo, Ylo, pk_mul(Zlo, Zlo)));
        v2f Whi = pk_fma(Xhi, Xhi, pk_fma(Yhi, Yhi, pk_mul(Zhi, Zhi)));
#pragma unroll
        for (int q = 0; q < QPT; ++q) {
            v2f t0 = pk_fma(Xlo, AX[q], pk_fma(Ylo, AY[q], pk_fma(Zlo, AZ[q], Wlo)));
            v2f t1 = pk_fma(Xhi, AX[q], pk_fma(Yhi, AY[q], pk_fma(Zhi, AZ[q], Whi)));
            acc[q] = min3f(t0.x, t0.y, min3f(t1.x, t1.y, acc[q]));
        }
    }

    // ---- store per-(z,chunk) partial mins (unique slots, coalesced) ----
    float* dst = partial + ((size_t)z * NCHUNK + blockIdx.y) * NPTS;
#pragma unroll
    for (int q = 0; q < QPT; ++q) {
        dst[jbase + q * TPB] = R[q] + acc[q];
    }
}

// min over the NCHUNK partials per query, huber, block partial-sum.
// 256 blocks x 256 threads: consecutive threads touch consecutive j (coalesced).
__global__ __launch_bounds__(256) void huber_kernel(const float* __restrict__ partial,
                                                    const float* __restrict__ cp,
                                                    float* __restrict__ bp) {
    const int s = blockIdx.x * 256 + threadIdx.x;   // [0, NZ*NPTS)
    const int z = s >> 12, j = s & (NPTS - 1);
    const float* p = partial + (size_t)z * NCHUNK * NPTS + j;
    float m = 3.4e38f;
#pragma unroll
    for (int c = 0; c < NCHUNK; ++c) m = fminf(m, p[(size_t)c * NPTS]);
    const float cc = cp[0];
    float h = (m < cc) ? (0.5f * m * m) : fmaf(cc, m, -0.5f * cc * cc);
    for (int off = 32; off > 0; off >>= 1) h += __shfl_down(h, off, 64);
    __shared__ float ls[4];
    if ((threadIdx.x & 63) == 0) ls[threadIdx.x >> 6] = h;
    __syncthreads();
    if (threadIdx.x == 0) bp[blockIdx.x] = ls[0] + ls[1] + ls[2] + ls[3];
}

__global__ __launch_bounds__(256) void final_kernel(const float* __restrict__ bp,
                                                    float* __restrict__ out) {
    float a = bp[threadIdx.x];   // exactly 256 block partials
    for (int off = 32; off > 0; off >>= 1) a += __shfl_down(a, off, 64);
    __shared__ float ls[4];
    if ((threadIdx.x & 63) == 0) ls[threadIdx.x >> 6] = a;
    __syncthreads();
    if (threadIdx.x == 0) out[0] = ls[0] + ls[1] + ls[2] + ls[3];
}

extern "C" void kernel_launch(void* const* d_in, const int* in_sizes, int n_in,
                              void* d_out, int out_size, void* d_ws, size_t ws_size,
                              hipStream_t stream) {
    const float* preds = (const float*)d_in[0];  // [8, 4096, 3]
    const float* gts   = (const float*)d_in[1];  // [8, 4096, 3]
    const float* cp    = (const float*)d_in[2];  // [1]
    float* out = (float*)d_out;

    float* partial = (float*)d_ws;                           // [NZ][NCHUNK][NPTS] = 8 MB
    float* bp      = partial + (size_t)NZ * NCHUNK * NPTS;   // [256]

    dim3 gm(XB, NCHUNK, NZ);   // (2, 32, 16) = 1024 blocks
    min_kernel<<<gm, TPB, 0, stream>>>(preds, gts, partial);

    huber_kernel<<<(NZ * NPTS) / 256, 256, 0, stream>>>(partial, cp, bp);
    final_kernel<<<1, 256, 0, stream>>>(bp, out);
}

// Round 10
// 32.627 us; speedup vs baseline: 1.4071x; 1.0236x over previous
//
#include <hip/hip_runtime.h>

typedef float v4f __attribute__((ext_vector_type(4)));

#define NPTS   4096
#define NZ     16                  // B * 2 passes
#define QPT    8                   // queries per thread
#define TPB    256
#define QPB    (TPB * QPT)         // 2048
#define XB     (NPTS / QPB)        // 2
#define CHUNK  128                 // points staged per block
#define NGRP   (CHUNK / 4)         // 32 groups of 4 points
#define NCHUNK (NPTS / CHUNK)      // 32

__device__ __forceinline__ float min3f(float a, float b, float c) {
    float d;
    asm("v_min3_f32 %0, %1, %2, %3" : "=v"(d) : "v"(a), "v"(b), "v"(c));
    return d;
}

// blockIdx: x = query slice (2), y = point chunk (32), z = b*2 + pass (16).
// Stage CHUNK points into LDS as 4-point SoA groups {x0..3},{y0..3},{z0..3},
// {w0..3} (w=|p|^2 precomputed at staging). Each thread computes the chunk-min
// for QPT queries with plain scalar fma chains (v_fma_f32 is the full-rate op
// on gfx950; packed f32 gains nothing) and stores to a unique partial slot.
__global__ __launch_bounds__(TPB, 4) void min_kernel(const float* __restrict__ preds,
                                                     const float* __restrict__ gts,
                                                     float* __restrict__ partial) {
    const int z    = blockIdx.z;
    const int b    = z >> 1;
    const int pass = z & 1;
    const int tid  = threadIdx.x;

    const float* pts = pass ? preds : gts;   // pass0: min over gts (per pred)
    const float* qrs = pass ? gts   : preds; // pass1: min over preds (per gt)

    __shared__ float SX[CHUNK], SY[CHUNK], SZ[CHUNK], SW[CHUNK];

    // ---- stage CHUNK points, transposed to 4-point SoA groups ----
    {
        const float* pb = pts + ((size_t)b * NPTS + blockIdx.y * CHUNK) * 3;
        if (tid < CHUNK) {
            float x  = pb[tid * 3 + 0];
            float y  = pb[tid * 3 + 1];
            float zz = pb[tid * 3 + 2];
            SX[tid] = x;
            SY[tid] = y;
            SZ[tid] = zz;
            SW[tid] = fmaf(x, x, fmaf(y, y, zz * zz));
        }
    }

    // ---- per-thread queries ----
    const float* qb    = qrs + (size_t)b * NPTS * 3;
    const int    jbase = blockIdx.x * QPB + tid;
    float ax[QPT], ay[QPT], az[QPT], R[QPT], acc[QPT];
#pragma unroll
    for (int q = 0; q < QPT; ++q) {
        int   j  = jbase + q * TPB;
        float qx = qb[j * 3 + 0];
        float qy = qb[j * 3 + 1];
        float qz = qb[j * 3 + 2];
        R[q]  = fmaf(qx, qx, fmaf(qy, qy, qz * qz));
        ax[q] = -2.0f * qx;
        ay[q] = -2.0f * qy;
        az[q] = -2.0f * qz;
        acc[q] = 3.4e38f;
    }
    __syncthreads();

    // ---- main loop: 4 points x QPT queries per group ----
    // per group: 4 broadcast ds_read_b128 (LDS pipe, ~48cy) feeding
    // 8q x (12 fma + 2 min3) = 112 VALU instrs (~224cy) -> VALU-bound.
#pragma unroll 2
    for (int g = 0; g < NGRP; ++g) {
        v4f X = *(const v4f*)&SX[4 * g];
        v4f Y = *(const v4f*)&SY[4 * g];
        v4f Z = *(const v4f*)&SZ[4 * g];
        v4f W = *(const v4f*)&SW[4 * g];
#pragma unroll
        for (int q = 0; q < QPT; ++q) {
            float t0 = fmaf(X.x, ax[q], fmaf(Y.x, ay[q], fmaf(Z.x, az[q], W.x)));
            float t1 = fmaf(X.y, ax[q], fmaf(Y.y, ay[q], fmaf(Z.y, az[q], W.y)));
            float t2 = fmaf(X.z, ax[q], fmaf(Y.z, ay[q], fmaf(Z.z, az[q], W.z)));
            float t3 = fmaf(X.w, ax[q], fmaf(Y.w, ay[q], fmaf(Z.w, az[q], W.w)));
            acc[q] = min3f(t0, t1, min3f(t2, t3, acc[q]));
        }
    }

    // ---- store per-(z,chunk) partial mins (unique slots, coalesced) ----
    float* dst = partial + ((size_t)z * NCHUNK + blockIdx.y) * NPTS;
#pragma unroll
    for (int q = 0; q < QPT; ++q) {
        dst[jbase + q * TPB] = R[q] + acc[q];
    }
}

// min over the NCHUNK partials per query, huber, block partial-sum.
// 256 blocks x 256 threads: consecutive threads touch consecutive j (coalesced).
__global__ __launch_bounds__(256) void huber_kernel(const float* __restrict__ partial,
                                                    const float* __restrict__ cp,
                                                    float* __restrict__ bp) {
    const int s = blockIdx.x * 256 + threadIdx.x;   // [0, NZ*NPTS)
    const int z = s >> 12, j = s & (NPTS - 1);
    const float* p = partial + (size_t)z * NCHUNK * NPTS + j;
    float m = 3.4e38f;
#pragma unroll
    for (int c = 0; c < NCHUNK; ++c) m = fminf(m, p[(size_t)c * NPTS]);
    const float cc = cp[0];
    float h = (m < cc) ? (0.5f * m * m) : fmaf(cc, m, -0.5f * cc * cc);
    for (int off = 32; off > 0; off >>= 1) h += __shfl_down(h, off, 64);
    __shared__ float ls[4];
    if ((threadIdx.x & 63) == 0) ls[threadIdx.x >> 6] = h;
    __syncthreads();
    if (threadIdx.x == 0) bp[blockIdx.x] = ls[0] + ls[1] + ls[2] + ls[3];
}

__global__ __launch_bounds__(256) void final_kernel(const float* __restrict__ bp,
                                                    float* __restrict__ out) {
    float a = bp[threadIdx.x];   // exactly 256 block partials
    for (int off = 32; off > 0; off >>= 1) a += __shfl_down(a, off, 64);
    __shared__ float ls[4];
    if ((threadIdx.x & 63) == 0) ls[threadIdx.x >> 6] = a;
    __syncthreads();
    if (threadIdx.x == 0) out[0] = ls[0] + ls[1] + ls[2] + ls[3];
}

extern "C" void kernel_launch(void* const* d_in, const int* in_sizes, int n_in,
                              void* d_out, int out_size, void* d_ws, size_t ws_size,
                              hipStream_t stream) {
    const float* preds = (const float*)d_in[0];  // [8, 4096, 3]
    const float* gts   = (const float*)d_in[1];  // [8, 4096, 3]
    const float* cp    = (const float*)d_in[2];  // [1]
    float* out = (float*)d_out;

    float* partial = (float*)d_ws;                           // [NZ][NCHUNK][NPTS] = 8 MB
    float* bp      = partial + (size_t)NZ * NCHUNK * NPTS;   // [256]

    dim3 gm(XB, NCHUNK, NZ);   // (2, 32, 16) = 1024 blocks
    min_kernel<<<gm, TPB, 0, stream>>>(preds, gts, partial);

    huber_kernel<<<(NZ * NPTS) / 256, 256, 0, stream>>>(partial, cp, bp);
    final_kernel<<<1, 256, 0, stream>>>(bp, out);
}